// Round 7
// baseline (211.708 us; speedup 1.0000x reference)
//
#include <hip/hip_runtime.h>
#include <hip/hip_bf16.h>

#define HID 128

typedef __attribute__((ext_vector_type(8))) short bf16x8;
typedef __attribute__((ext_vector_type(4))) float f32x4;

__device__ inline unsigned short f2bf(float f) {
    unsigned u = __float_as_uint(f);
    u += 0x7fffu + ((u >> 16) & 1u);   // RNE
    return (unsigned short)(u >> 16);
}
__device__ inline float bfval(unsigned short s) {
    return __uint_as_float(((unsigned)s) << 16);
}

// ---------------- CSR build ----------------

__global__ void deg_init_kernel(int* deg, int N) {
    int i = blockIdx.x * blockDim.x + threadIdx.x;
    if (i < N) deg[i] = 1;  // self loop
}

__global__ void deg_count_kernel(const int* __restrict__ dst, int E, int* deg) {
    int i = blockIdx.x * blockDim.x + threadIdx.x;
    if (i < E) atomicAdd(&deg[dst[i]], 1);
}

__global__ __launch_bounds__(256) void scan1_kernel(const int* __restrict__ deg,
                                                    int* __restrict__ bsum, int N) {
    int tid = threadIdx.x;
    int i = blockIdx.x * 256 + tid;
    int v = (i < N) ? deg[i] : 0;
    #pragma unroll
    for (int off = 1; off < 64; off <<= 1) v += __shfl_xor(v, off);
    __shared__ int ws[4];
    if ((tid & 63) == 0) ws[tid >> 6] = v;
    __syncthreads();
    if (tid == 0) bsum[blockIdx.x] = ws[0] + ws[1] + ws[2] + ws[3];
}

__global__ __launch_bounds__(256) void scan2_kernel(const int* __restrict__ bsum,
                                                    int* __restrict__ boff,
                                                    int* __restrict__ row_ptr, int NB, int N) {
    __shared__ int s[256];
    int tid = threadIdx.x;
    int v = (tid < NB) ? bsum[tid] : 0;
    s[tid] = v;
    __syncthreads();
    for (int off = 1; off < 256; off <<= 1) {
        int t = (tid >= off) ? s[tid - off] : 0;
        __syncthreads();
        s[tid] += t;
        __syncthreads();
    }
    if (tid < NB) boff[tid] = s[tid] - v;  // exclusive
    if (tid == NB - 1) row_ptr[N] = s[tid];
}

__global__ __launch_bounds__(256) void scan3_kernel(const int* __restrict__ deg,
                                                    const int* __restrict__ boff,
                                                    int* __restrict__ row_ptr,
                                                    int* __restrict__ cursor,
                                                    int* __restrict__ col, int N) {
    __shared__ int s[256];
    int tid = threadIdx.x;
    int i = blockIdx.x * 256 + tid;
    int d = (i < N) ? deg[i] : 0;
    s[tid] = d;
    __syncthreads();
    for (int off = 1; off < 256; off <<= 1) {
        int t = (tid >= off) ? s[tid - off] : 0;
        __syncthreads();
        s[tid] += t;
        __syncthreads();
    }
    if (i < N) {
        int run = boff[blockIdx.x] + s[tid] - d;  // exclusive prefix
        row_ptr[i] = run;
        cursor[i] = run + 1;  // slot 0 taken by self loop
        col[run] = i;         // self loop
    }
}

__global__ void scatter_kernel(const int* __restrict__ src, const int* __restrict__ dst,
                               int E, int* cursor, int* col) {
    int i = blockIdx.x * blockDim.x + threadIdx.x;
    if (i < E) {
        int pos = atomicAdd(&cursor[dst[i]], 1);
        col[pos] = src[i];
    }
}

// ---------------- prep: x -> bf16 ----------------
__global__ void tobf16_kernel(const float* __restrict__ x, ushort* __restrict__ xs, int n8) {
    int i = blockIdx.x * blockDim.x + threadIdx.x;   // one per 8 elems
    if (i >= n8) return;
    size_t b = (size_t)i * 8;
    float4 v0 = *(const float4*)&x[b];
    float4 v1 = *(const float4*)&x[b + 4];
    uint4 o;
    o.x = (unsigned)f2bf(v0.x) | ((unsigned)f2bf(v0.y) << 16);
    o.y = (unsigned)f2bf(v0.z) | ((unsigned)f2bf(v0.w) << 16);
    o.z = (unsigned)f2bf(v1.x) | ((unsigned)f2bf(v1.y) << 16);
    o.w = (unsigned)f2bf(v1.z) | ((unsigned)f2bf(v1.w) << 16);
    *(uint4*)&xs[b] = o;
}

// ---------------- prep: W -> MFMA frag layout, hi/lo split ----------------
// wbuf[layer][p][s][t][lane][j]  (ushort), p=0: bf16(W), p=1: bf16(W - hi)
// frag element j for lane l: k = s*32 + (l>>4)*8 + j, c = t*16 + (l&15)
__global__ void prep_w_kernel(const float* __restrict__ W1, const float* __restrict__ W2,
                              const float* __restrict__ W3, ushort* __restrict__ wbuf) {
    int t = blockIdx.x * blockDim.x + threadIdx.x;   // 0 .. 3*4096-1
    if (t >= 3 * 4096) return;
    int layer = t >> 12;
    int rem = t & 4095;
    int lane = rem & 63;
    int tt = (rem >> 6) & 7;
    int s = (rem >> 9) & 3;
    int p = rem >> 11;
    const float* W = (layer == 0) ? W1 : (layer == 1) ? W2 : W3;
    int k0 = s * 32 + (lane >> 4) * 8;
    int c = tt * 16 + (lane & 15);
    ushort out[8];
    #pragma unroll
    for (int j = 0; j < 8; ++j) {
        float w = W[(size_t)(k0 + j) * HID + c];
        unsigned short hi = f2bf(w);
        out[j] = (p == 0) ? hi : f2bf(w - bfval(hi));
    }
    size_t base = (size_t)layer * 32768 + ((((size_t)p * 4 + s) * 8 + tt) * 64 + lane) * 8;
    *(uint4*)&wbuf[base] = *(uint4*)out;
}

// ---------------- MFMA GEMM + fused alphas (register-resident W, no LDS loop) ----------------
// block = 256 thr = 4 waves, 64 rows. Wave w owns col-tiles {2w, 2w+1} (32 ch) of all
// 64 rows: W frags (2p x 4s x 2t = 64 VGPR) from global, x frags (4rg x 4s), 64 MFMA,
// no ds_read / no barrier in main loop. H=4: wave w == head w, alpha reduce = 2 shfl.
// H=1: 4 wave-partials combined via 2 KB LDS.
template <int H>
__global__ __launch_bounds__(256) void mfma_gemm_kernel(const ushort* __restrict__ xs,
                                                        const ushort* __restrict__ wbuf,
                                                        const float* __restrict__ a_src,
                                                        const float* __restrict__ a_dst,
                                                        ushort* __restrict__ h,
                                                        float* __restrict__ pa_out,
                                                        float* __restrict__ pd_out, int N) {
    __shared__ float part[4][64][2];   // used only for H==1 cross-wave alpha combine
    int tid = threadIdx.x;
    int wv = tid >> 6, lane = tid & 63;
    int r0 = blockIdx.x * 64;
    int cg = lane >> 4;          // k-group / channel-group
    int lr = lane & 15;          // row-in-group

    // W frags for this wave's two tiles
    bf16x8 wf[2][4][2];          // [p][s][tt]
    #pragma unroll
    for (int p = 0; p < 2; ++p)
        #pragma unroll
        for (int s = 0; s < 4; ++s)
            #pragma unroll
            for (int tt = 0; tt < 2; ++tt)
                wf[p][s][tt] = *(const bf16x8*)&wbuf[((((p * 4 + s) * 8) + 2 * wv + tt) * 64 + lane) * 8];

    // x frags: rows r0 + rg*16 + lr, k = cg*8 + s*32 + j
    bf16x8 xf[4][4];             // [rg][s]
    #pragma unroll
    for (int rg = 0; rg < 4; ++rg) {
        int row = r0 + rg * 16 + lr;
        if (row >= N) row = N - 1;
        const ushort* xp = &xs[(size_t)row * HID + cg * 8];
        #pragma unroll
        for (int s = 0; s < 4; ++s) xf[rg][s] = *(const bf16x8*)&xp[s * 32];
    }

    f32x4 acc[4][2];             // [rg][tt]
    #pragma unroll
    for (int rg = 0; rg < 4; ++rg)
        #pragma unroll
        for (int tt = 0; tt < 2; ++tt) acc[rg][tt] = (f32x4){0.f, 0.f, 0.f, 0.f};

    #pragma unroll
    for (int rg = 0; rg < 4; ++rg)
        #pragma unroll
        for (int p = 0; p < 2; ++p)
            #pragma unroll
            for (int s = 0; s < 4; ++s)
                #pragma unroll
                for (int tt = 0; tt < 2; ++tt)
                    acc[rg][tt] = __builtin_amdgcn_mfma_f32_16x16x32_bf16(
                        wf[p][s][tt], xf[rg][s], acc[rg][tt], 0, 0, 0);

    // epilogue: D col(lane&15)=row, D row(cg*4+j)=channel within tile 2wv+tt
    #pragma unroll
    for (int rg = 0; rg < 4; ++rg) {
        int row = r0 + rg * 16 + lr;
        bool ok = row < N;
        if (ok) {
            #pragma unroll
            for (int tt = 0; tt < 2; ++tt) {
                uint2 pk;
                pk.x = (unsigned)f2bf(acc[rg][tt][0]) | ((unsigned)f2bf(acc[rg][tt][1]) << 16);
                pk.y = (unsigned)f2bf(acc[rg][tt][2]) | ((unsigned)f2bf(acc[rg][tt][3]) << 16);
                *(uint2*)&h[(size_t)row * HID + (2 * wv + tt) * 16 + cg * 4] = pk;
            }
        }
        float sa = 0.f, sd = 0.f;
        #pragma unroll
        for (int tt = 0; tt < 2; ++tt) {
            int ch = (2 * wv + tt) * 16 + cg * 4;
            float4 av = *(const float4*)&a_src[ch];
            float4 dv = *(const float4*)&a_dst[ch];
            sa += acc[rg][tt][0] * av.x + acc[rg][tt][1] * av.y +
                  acc[rg][tt][2] * av.z + acc[rg][tt][3] * av.w;
            sd += acc[rg][tt][0] * dv.x + acc[rg][tt][1] * dv.y +
                  acc[rg][tt][2] * dv.z + acc[rg][tt][3] * dv.w;
        }
        sa += __shfl_xor(sa, 16); sa += __shfl_xor(sa, 32);
        sd += __shfl_xor(sd, 16); sd += __shfl_xor(sd, 32);
        if (H == 4) {
            if (ok && cg == 0) {
                pa_out[(size_t)row * 4 + wv] = sa;
                pd_out[(size_t)row * 4 + wv] = sd;
            }
        } else {
            if (lane < 16) {
                part[wv][rg * 16 + lr][0] = sa;
                part[wv][rg * 16 + lr][1] = sd;
            }
        }
    }
    if (H == 1) {
        __syncthreads();
        if (tid < 128) {
            int r = tid >> 1, c = tid & 1;
            float v = part[0][r][c] + part[1][r][c] + part[2][r][c] + part[3][r][c];
            int row = r0 + r;
            if (row < N) {
                if (c) pd_out[row] = v; else pa_out[row] = v;
            }
        }
    }
}

// ---------------- aggregation: wave per dst node, online softmax, bf16 gather ----------------
template <int H, bool RELU, bool OUTBF>
__global__ __launch_bounds__(256) void aggregate_kernel(const ushort* __restrict__ h,
                                                        const float* __restrict__ asrc,
                                                        const float* __restrict__ adst,
                                                        const int* __restrict__ row_ptr,
                                                        const int* __restrict__ col,
                                                        const float* __restrict__ bias,
                                                        void* __restrict__ outv, int N) {
    int lane = threadIdx.x & 63;
    int node = blockIdx.x * (blockDim.x >> 6) + (threadIdx.x >> 6);
    if (node >= N) return;

    int start = row_ptr[node];
    int end   = row_ptr[node + 1];

    constexpr int EPC = 64 / H;        // edges per score chunk
    int ehd = lane % H;                // score phase: head
    int eidx = lane / H;               // score phase: edge slot
    int q  = lane >> 4;                // gather: quarter-wave = edge of quad
    int cl = lane & 15;                // gather: channels 8cl..8cl+7
    int ahd = (cl * H) >> 4;           // head owning those channels

    float adst_n = adst[(size_t)node * H + ehd];

    float m = -INFINITY, denom = 0.f;
    float acc[8] = {0.f, 0.f, 0.f, 0.f, 0.f, 0.f, 0.f, 0.f};

    for (int base = start; base < end; base += EPC) {
        int idx = base + eidx;
        bool valid = idx < end;
        int s = valid ? col[idx] : 0;
        int cnt = min(end - base, EPC);

        if (H == 4) {
            // issue gather addresses + loads BEFORE the score shuffle chain
            int s0 = __shfl(s, (0 + q) * H);
            int s1 = __shfl(s, (4 + q) * H);
            int s2 = __shfl(s, (8 + q) * H);
            int s3 = __shfl(s, (12 + q) * H);
            bool v0 = (0 + q) < cnt, v1 = (4 + q) < cnt, v2 = (8 + q) < cnt, v3 = (12 + q) < cnt;
            uint4 hv0, hv1, hv2, hv3;
            if (v0) hv0 = *(const uint4*)&h[(size_t)s0 * HID + cl * 8];
            if (v1) hv1 = *(const uint4*)&h[(size_t)s1 * HID + cl * 8];
            if (v2) hv2 = *(const uint4*)&h[(size_t)s2 * HID + cl * 8];
            if (v3) hv3 = *(const uint4*)&h[(size_t)s3 * HID + cl * 8];

            float e = -INFINITY;
            if (valid) {
                float t = asrc[(size_t)s * H + ehd] + adst_n;
                e = (t >= 0.f) ? t : 0.2f * t;
            }
            float cmax = e;
            #pragma unroll
            for (int off = H; off < 64; off <<= 1) cmax = fmaxf(cmax, __shfl_xor(cmax, off));
            float nm = fmaxf(m, cmax);
            float p = valid ? __expf(e - nm) : 0.f;
            float csum = p;
            #pragma unroll
            for (int off = H; off < 64; off <<= 1) csum += __shfl_xor(csum, off);
            float scale_e = __expf(m - nm);
            denom = denom * scale_e + csum;
            m = nm;
            float sa = __shfl(scale_e, ahd);
            #pragma unroll
            for (int k = 0; k < 8; ++k) acc[k] *= sa;

            float p0 = __shfl(p, (0 + q) * H + ahd);
            float p1 = __shfl(p, (4 + q) * H + ahd);
            float p2 = __shfl(p, (8 + q) * H + ahd);
            float p3 = __shfl(p, (12 + q) * H + ahd);
            #define ACC_EDGE(hv, pi)                                     \
                { acc[0] += pi * __uint_as_float(hv.x << 16);            \
                  acc[1] += pi * __uint_as_float(hv.x & 0xffff0000u);    \
                  acc[2] += pi * __uint_as_float(hv.y << 16);            \
                  acc[3] += pi * __uint_as_float(hv.y & 0xffff0000u);    \
                  acc[4] += pi * __uint_as_float(hv.z << 16);            \
                  acc[5] += pi * __uint_as_float(hv.z & 0xffff0000u);    \
                  acc[6] += pi * __uint_as_float(hv.w << 16);            \
                  acc[7] += pi * __uint_as_float(hv.w & 0xffff0000u); }
            if (v0) ACC_EDGE(hv0, p0)
            if (v1) ACC_EDGE(hv1, p1)
            if (v2) ACC_EDGE(hv2, p2)
            if (v3) ACC_EDGE(hv3, p3)
        } else {
            float e = -INFINITY;
            if (valid) {
                float t = asrc[(size_t)s * H + ehd] + adst_n;
                e = (t >= 0.f) ? t : 0.2f * t;
            }
            float cmax = e;
            #pragma unroll
            for (int off = H; off < 64; off <<= 1) cmax = fmaxf(cmax, __shfl_xor(cmax, off));
            float nm = fmaxf(m, cmax);
            float p = valid ? __expf(e - nm) : 0.f;
            float csum = p;
            #pragma unroll
            for (int off = H; off < 64; off <<= 1) csum += __shfl_xor(csum, off);
            float scale_e = __expf(m - nm);
            denom = denom * scale_e + csum;
            m = nm;
            float sa = __shfl(scale_e, ahd);
            #pragma unroll
            for (int k = 0; k < 8; ++k) acc[k] *= sa;

            for (int i = 0; i < cnt; i += 4) {
                int slot = i + q;
                int   si = __shfl(s, slot * H);
                float pi = __shfl(p, slot * H + ahd);
                if (slot < cnt) {
                    uint4 hv = *(const uint4*)&h[(size_t)si * HID + cl * 8];
                    ACC_EDGE(hv, pi)
                }
            }
        }
    }
    // combine the four quarter-wave accumulators
    #pragma unroll
    for (int off = 16; off < 64; off <<= 1) {
        #pragma unroll
        for (int k = 0; k < 8; ++k) acc[k] += __shfl_xor(acc[k], off);
    }

    float den = __shfl(denom, ahd);
    if (lane < 16) {
        float inv = 1.f / den;
        float o[8];
        #pragma unroll
        for (int k = 0; k < 8; ++k) {
            o[k] = acc[k] * inv + bias[cl * 8 + k];
            if (RELU) o[k] = fmaxf(o[k], 0.f);
        }
        if (OUTBF) {
            uint4 ov;
            ov.x = (unsigned)f2bf(o[0]) | ((unsigned)f2bf(o[1]) << 16);
            ov.y = (unsigned)f2bf(o[2]) | ((unsigned)f2bf(o[3]) << 16);
            ov.z = (unsigned)f2bf(o[4]) | ((unsigned)f2bf(o[5]) << 16);
            ov.w = (unsigned)f2bf(o[6]) | ((unsigned)f2bf(o[7]) << 16);
            *(uint4*)&((ushort*)outv)[(size_t)node * HID + cl * 8] = ov;
        } else {
            float* op = &((float*)outv)[(size_t)node * HID + cl * 8];
            *(float4*)op = make_float4(o[0], o[1], o[2], o[3]);
            *(float4*)(op + 4) = make_float4(o[4], o[5], o[6], o[7]);
        }
    }
}

// ---------------- launch ----------------

extern "C" void kernel_launch(void* const* d_in, const int* in_sizes, int n_in,
                              void* d_out, int out_size, void* d_ws, size_t ws_size,
                              hipStream_t stream) {
    const float* x   = (const float*)d_in[0];
    const int*   ei  = (const int*)d_in[1];
    const float* W1  = (const float*)d_in[2];
    const float* as1 = (const float*)d_in[3];
    const float* ad1 = (const float*)d_in[4];
    const float* b1  = (const float*)d_in[5];
    const float* W2  = (const float*)d_in[6];
    const float* as2 = (const float*)d_in[7];
    const float* ad2 = (const float*)d_in[8];
    const float* b2  = (const float*)d_in[9];
    const float* W3  = (const float*)d_in[10];
    const float* as3 = (const float*)d_in[11];
    const float* ad3 = (const float*)d_in[12];
    const float* b3  = (const float*)d_in[13];

    int N = in_sizes[0] / HID;
    int E = in_sizes[1] / 2;
    const int* srcv = ei;
    const int* dstv = ei + E;

    char* ws = (char*)d_ws;
    size_t ofs = 0;
    auto alloc = [&](size_t bytes) -> void* {
        void* p = ws + ofs;
        ofs = (ofs + bytes + 255) & ~(size_t)255;
        return p;
    };
    int NB = (N + 255) / 256;
    int*    rp   = (int*)alloc((size_t)(N + 1) * 4);
    int*    cur  = (int*)alloc((size_t)N * 4);
    int*    deg  = (int*)alloc((size_t)N * 4);
    int*    bsum = (int*)alloc((size_t)NB * 4);
    int*    boff = (int*)alloc((size_t)NB * 4);
    int*    col  = (int*)alloc((size_t)(E + N) * 4);
    ushort* xs   = (ushort*)alloc((size_t)N * HID * 2);   // layer1 input (bf16)
    ushort* ys   = (ushort*)alloc((size_t)N * HID * 2);   // layer2 input
    ushort* hb   = (ushort*)alloc((size_t)N * HID * 2);   // per-layer h (bf16)
    ushort* wbuf = (ushort*)alloc((size_t)3 * 32768 * 2); // W frag layout (hi+lo) x3
    float*  pa   = (float*)alloc((size_t)N * 4 * 4);
    float*  pd   = (float*)alloc((size_t)N * 4 * 4);

    // CSR build
    deg_init_kernel<<<(N + 255) / 256, 256, 0, stream>>>(deg, N);
    deg_count_kernel<<<(E + 255) / 256, 256, 0, stream>>>(dstv, E, deg);
    scan1_kernel<<<NB, 256, 0, stream>>>(deg, bsum, N);
    scan2_kernel<<<1, 256, 0, stream>>>(bsum, boff, rp, NB, N);
    scan3_kernel<<<NB, 256, 0, stream>>>(deg, boff, rp, cur, col, N);
    scatter_kernel<<<(E + 255) / 256, 256, 0, stream>>>(srcv, dstv, E, cur, col);

    // prep
    int n8 = N * HID / 8;
    tobf16_kernel<<<(n8 + 255) / 256, 256, 0, stream>>>(x, xs, n8);
    prep_w_kernel<<<(3 * 4096 + 255) / 256, 256, 0, stream>>>(W1, W2, W3, wbuf);

    int gGemm = (N + 63) / 64;
    int gWave = (N + 3) / 4;

    // layer 1 (4 heads, relu) -> ys
    mfma_gemm_kernel<4><<<gGemm, 256, 0, stream>>>(xs, wbuf, as1, ad1, hb, pa, pd, N);
    aggregate_kernel<4, true, true><<<gWave, 256, 0, stream>>>(hb, pa, pd, rp, col, b1, ys, N);
    // layer 2 (4 heads, relu) -> xs (reuse)
    mfma_gemm_kernel<4><<<gGemm, 256, 0, stream>>>(ys, wbuf + 32768, as2, ad2, hb, pa, pd, N);
    aggregate_kernel<4, true, true><<<gWave, 256, 0, stream>>>(hb, pa, pd, rp, col, b2, xs, N);
    // layer 3 (1 head, no relu) -> d_out fp32
    mfma_gemm_kernel<1><<<gGemm, 256, 0, stream>>>(xs, wbuf + 65536, as3, ad3, hb, pa, pd, N);
    aggregate_kernel<1, false, false><<<gWave, 256, 0, stream>>>(hb, pa, pd, rp, col, b3,
                                                                 d_out, N);
}